// Round 6
// baseline (230.709 us; speedup 1.0000x reference)
//
#include <hip/hip_runtime.h>
#include <hip/hip_bf16.h>

typedef _Float16 f16x8 __attribute__((ext_vector_type(8)));
typedef _Float16 f16x4 __attribute__((ext_vector_type(4)));
typedef float f32x4 __attribute__((ext_vector_type(4)));

__device__ __forceinline__ void async_ld16(_Float16* lds, const _Float16* g) {
    __builtin_amdgcn_global_load_lds(
        (const __attribute__((address_space(1))) void*)g,
        (__attribute__((address_space(3))) void*)lds, 16, 0, 0);
}

// C = A[M,K] * B[N,K]^T  (k-contiguous fp16 -> fp32), 128x128 tile, 4 waves
// 2x2, each wave 64x64 via 4x4 of 16x16x32 MFMA. Double-buffered LDS.
// XCD-aware swizzle (bid&7 = XCD; verified: FETCH 154->49MB): per XCD, sweep
// one 128-row A-band across all columns; B streams via L3.
// accum=0: plain+NT store (S). accum=1: atomicAdd into C (split-K direct).
__global__ __launch_bounds__(256) void gemm_bt(
    const _Float16* __restrict__ A,
    const _Float16* __restrict__ B,
    float* __restrict__ C,
    int M, int N, int Ks, int lda, int ldb, int ldc, int accum)
{
    __shared__ _Float16 At[2][128 * 32];
    __shared__ _Float16 Bt[2][128 * 32];

    const int tid  = threadIdx.x;
    const int wave = tid >> 6;
    const int lane = tid & 63;

    const int gx = gridDim.x, gy = gridDim.y;
    int bx = blockIdx.x, by = blockIdx.y;
    if ((gy & 7) == 0) {
        const int bid = bx + gx * by;
        const int x = bid & 7;           // XCD id (bid%8 round-robin)
        const int j = bid >> 3;
        bx = j % gx;
        by = x + 8 * (j / gx);
    }
    const int row0 = by * 128;
    const int col0 = bx * 128;

    const int wr = (wave >> 1) * 64;
    const int wc = (wave & 1) * 64;
    const int quad = lane >> 4;
    const int l16  = lane & 15;

    f32x4 acc[4][4] = {};

    // staging: wave w fills LDS row-chunks w and w+4 (16 rows x 64B each);
    // global_load_lds dest = wave-uniform base + lane*16.
    const int srow  = lane >> 2;
    const int skoff = (lane & 3) * 8;
    const size_t K64a = (size_t)64 * lda;
    const size_t K64b = (size_t)64 * ldb;

    const int z = blockIdx.z;
    const _Float16* Ab = A + (size_t)row0 * lda + (size_t)z * Ks;
    const _Float16* Bb = B + (size_t)col0 * ldb + (size_t)z * Ks;

    const _Float16* pa = Ab + (size_t)(wave * 16 + srow) * lda + skoff;
    const _Float16* pb = Bb + (size_t)(wave * 16 + srow) * ldb + skoff;

    async_ld16(At[0] + wave * 512,       pa);
    async_ld16(At[0] + (wave + 4) * 512, pa + K64a);
    async_ld16(Bt[0] + wave * 512,       pb);
    async_ld16(Bt[0] + (wave + 4) * 512, pb + K64b);
    __syncthreads();

    int cur = 0;
    for (int k0 = 0; k0 < Ks; k0 += 32) {
        const int nxt = cur ^ 1;
        if (k0 + 32 < Ks) {
            const _Float16* qa = pa + k0 + 32;
            const _Float16* qb = pb + k0 + 32;
            async_ld16(At[nxt] + wave * 512,       qa);
            async_ld16(At[nxt] + (wave + 4) * 512, qa + K64a);
            async_ld16(Bt[nxt] + wave * 512,       qb);
            async_ld16(Bt[nxt] + (wave + 4) * 512, qb + K64b);
        }

        f16x8 af[4], bf[4];
        #pragma unroll
        for (int r = 0; r < 4; ++r)
            af[r] = *(const f16x8*)&At[cur][(wr + r * 16 + l16) * 32 + quad * 8];
        #pragma unroll
        for (int c = 0; c < 4; ++c)
            bf[c] = *(const f16x8*)&Bt[cur][(wc + c * 16 + l16) * 32 + quad * 8];

        #pragma unroll
        for (int r = 0; r < 4; ++r)
            #pragma unroll
            for (int c = 0; c < 4; ++c)
                acc[r][c] = __builtin_amdgcn_mfma_f32_16x16x32_f16(af[r], bf[c], acc[r][c], 0, 0, 0);

        __syncthreads();
        cur = nxt;
    }

    // C/D layout: col = lane&15, row = quad*4 + reg   [verified m89/m91]
    #pragma unroll
    for (int r = 0; r < 4; ++r) {
        const int growb = row0 + wr + r * 16 + quad * 4;
        #pragma unroll
        for (int c = 0; c < 4; ++c) {
            const int gcol = col0 + wc + c * 16 + l16;
            if (accum) {
                #pragma unroll
                for (int i = 0; i < 4; ++i)
                    atomicAdd(&C[(size_t)(growb + i) * ldc + gcol], acc[r][c][i]);
            } else {
                #pragma unroll
                for (int i = 0; i < 4; ++i)
                    __builtin_nontemporal_store(
                        acc[r][c][i], &C[(size_t)(growb + i) * ldc + gcol]);
            }
        }
    }
}

// one block per row; reads S f32 row [4096], writes P fp16 IN PLACE over the
// first half of the row (all reads complete before first barrier -> safe).
__global__ __launch_bounds__(256) void softmax_rows(
    float* __restrict__ S, float scale)
{
    __shared__ float red[4];
    const int row = blockIdx.x;
    const int tid = threadIdx.x;
    const int wave = tid >> 6;
    const float4* Sr = (const float4*)(S + (size_t)row * 4096);

    float4 x[4];
    #pragma unroll
    for (int i = 0; i < 4; ++i) x[i] = Sr[tid + i * 256];

    float mx = -3.402823466e+38f;
    #pragma unroll
    for (int i = 0; i < 4; ++i)
        mx = fmaxf(mx, fmaxf(fmaxf(x[i].x, x[i].y), fmaxf(x[i].z, x[i].w)));
    #pragma unroll
    for (int off = 32; off > 0; off >>= 1) mx = fmaxf(mx, __shfl_down(mx, off));
    if ((tid & 63) == 0) red[wave] = mx;
    __syncthreads();
    mx = fmaxf(fmaxf(red[0], red[1]), fmaxf(red[2], red[3]));
    __syncthreads();

    float sum = 0.0f;
    #pragma unroll
    for (int i = 0; i < 4; ++i) {
        x[i].x = __expf(x[i].x - mx);
        x[i].y = __expf(x[i].y - mx);
        x[i].z = __expf(x[i].z - mx);
        x[i].w = __expf(x[i].w - mx);
        sum += x[i].x + x[i].y + x[i].z + x[i].w;
    }
    #pragma unroll
    for (int off = 32; off > 0; off >>= 1) sum += __shfl_down(sum, off);
    if ((tid & 63) == 0) red[wave] = sum;
    __syncthreads();
    sum = red[0] + red[1] + red[2] + red[3];

    const float inv = scale / sum;
    f16x4* Pr = (f16x4*)((_Float16*)S + (size_t)row * 8192);
    #pragma unroll
    for (int i = 0; i < 4; ++i) {
        f16x4 h;
        h.x = (_Float16)(x[i].x * inv);
        h.y = (_Float16)(x[i].y * inv);
        h.z = (_Float16)(x[i].z * inv);
        h.w = (_Float16)(x[i].w * inv);
        Pr[tid + i * 256] = h;
    }
}

// fused prep: [0,4096) transpose-cvt V tiles; [4096,6144) cvt Q,K to fp16;
// [6144,8192) zero out (PV accumulates into it atomically).
__global__ __launch_bounds__(256) void prep(
    const float* __restrict__ Q, _Float16* __restrict__ Qh, int nQ4,   // n*d/4
    const float* __restrict__ Kf, _Float16* __restrict__ Kh, int nK4,  // m*d/4
    const float* __restrict__ V, _Float16* __restrict__ Vt, int rows, int cols,
    float4* __restrict__ outz, int nz4)
{
    const int bid = blockIdx.x;
    if (bid < 4096) {
        // transpose 32x32 tile of V: Vt[c][r] = V[r][c]
        __shared__ float tile[32][33];
        const int c0 = (bid & 31) * 32;          // cols/32 == 32
        const int r0 = (bid >> 5) * 32;
        const int tx = threadIdx.x & 31;
        const int ty = threadIdx.x >> 5;
        #pragma unroll
        for (int i = 0; i < 4; ++i)
            tile[ty * 4 + i][tx] = V[(size_t)(r0 + ty * 4 + i) * cols + c0 + tx];
        __syncthreads();
        #pragma unroll
        for (int i = 0; i < 4; ++i)
            Vt[(size_t)(c0 + ty * 4 + i) * rows + r0 + tx] = (_Float16)tile[tx][ty * 4 + i];
    } else if (bid < 6144) {
        int i = (bid - 4096) * 256 + threadIdx.x;
        const int stride = 2048 * 256;
        const int tot = nQ4 + nK4;
        const float4* a = (const float4*)Q;
        const float4* b = (const float4*)Kf;
        for (; i < tot; i += stride) {
            const float4* s = (i < nQ4) ? (a + i) : (b + (i - nQ4));
            f16x4* dd = (i < nQ4) ? ((f16x4*)Qh + i) : ((f16x4*)Kh + (i - nQ4));
            float4 v = *s;
            f16x4 h;
            h.x = (_Float16)v.x; h.y = (_Float16)v.y;
            h.z = (_Float16)v.z; h.w = (_Float16)v.w;
            *dd = h;
        }
    } else {
        int i = (bid - 6144) * 256 + threadIdx.x;
        const int stride = 2048 * 256;
        const float4 zero = {0.f, 0.f, 0.f, 0.f};
        for (; i < nz4; i += stride) outz[i] = zero;
    }
}

extern "C" void kernel_launch(void* const* d_in, const int* in_sizes, int n_in,
                              void* d_out, int out_size, void* d_ws, size_t ws_size,
                              hipStream_t stream) {
    const float* Q = (const float*)d_in[0];
    const float* K = (const float*)d_in[1];
    const float* V = (const float*)d_in[2];
    float* out = (float*)d_out;

    const int n = 4096, m = 4096, d = 1024, vdim = 1024;
    const float scale = 0.03125f;  // 1024^-0.5

    char* w = (char*)d_ws;
    _Float16* Qh = (_Float16*)w;                        // 8 MB
    _Float16* Kh = (_Float16*)(w + (8u << 20));         // 8 MB
    _Float16* Vt = (_Float16*)(w + (16u << 20));        // 8 MB
    char* rest = w + (24u << 20);
    size_t avail = ws_size > (24u << 20) ? ws_size - (24u << 20) : 0;

    // chunk footprint: S = nc rows x 16 KB (f32 4096-wide; P fp16 overwrites
    // first half in place). Split-K partials go straight to out via atomics.
    int nc, sk;
    if      (avail >= (size_t)4096 * 16384) { nc = 4096; sk = 2; }
    else if (avail >= (size_t)2048 * 16384) { nc = 2048; sk = 4; }
    else if (avail >= (size_t)1024 * 16384) { nc = 1024; sk = 4; }
    else                                    { nc = 512;  sk = 4; }

    float* S = (float*)rest;                      // nc x 4096 f32

    prep<<<dim3(8192), dim3(256), 0, stream>>>(
        Q, Qh, n * d / 4, K, Kh, m * d / 4, V, Vt, m, vdim,
        (float4*)out, n * vdim / 4);

    for (int r0 = 0; r0 < n; r0 += nc) {
        // S = Qc * Kh^T   [nc x m]
        gemm_bt<<<dim3(m / 128, nc / 128, 1), dim3(256), 0, stream>>>(
            Qh + (size_t)r0 * d, Kh, S, nc, m, d, d, d, m, 0);

        softmax_rows<<<dim3(nc), dim3(256), 0, stream>>>(S, scale);

        // out[chunk] += P * Vt^T  (split-K over keys, atomic accumulate)
        gemm_bt<<<dim3(vdim / 128, nc / 128, sk), dim3(256), 0, stream>>>(
            (const _Float16*)S, Vt, out + (size_t)r0 * vdim,
            nc, vdim, m / sk, 2 * m, m, vdim, 1);
    }
}

// Round 7
// 224.702 us; speedup vs baseline: 1.0267x; 1.0267x over previous
//
#include <hip/hip_runtime.h>
#include <hip/hip_bf16.h>

typedef _Float16 f16x8 __attribute__((ext_vector_type(8)));
typedef _Float16 f16x4 __attribute__((ext_vector_type(4)));
typedef float f32x4 __attribute__((ext_vector_type(4)));

__device__ __forceinline__ void async_ld16(_Float16* lds, const _Float16* g) {
    __builtin_amdgcn_global_load_lds(
        (const __attribute__((address_space(1))) void*)g,
        (__attribute__((address_space(3))) void*)lds, 16, 0, 0);
}

// per-z C destinations (pointer + row stride in f32 elements)
struct CDesc {
    float *p0, *p1, *p2, *p3;
    int l0, l1, l2, l3;
};

// C = A[rows,K] * B[cols,K]^T, 256x128 tile, 8 waves (512 thr) as 4x2,
// each wave 64x64 via 4x4 of 16x16x32 MFMA. Double-buffered LDS (48 KB,
// 3 blocks/CU). Rationale: per-iteration barrier+vmcnt drain is ~constant,
// so fatter tiles halve block-iters -> ~2x MFMA per drain.
// XCD swizzle (bid&7=XCD, verified FETCH 154->49MB). NT stores (accum-free).
__global__ __launch_bounds__(512) void gemm256(
    const _Float16* __restrict__ A,
    const _Float16* __restrict__ B,
    int Ks, int lda, int ldb, CDesc cd)
{
    __shared__ _Float16 At[2][256 * 32];
    __shared__ _Float16 Bt[2][128 * 32];

    const int tid  = threadIdx.x;
    const int wave = tid >> 6;           // 0..7
    const int lane = tid & 63;

    const int gx = gridDim.x;
    int bx = blockIdx.x, by = blockIdx.y;
    if ((gridDim.y & 7) == 0) {
        const int bid = bx + gx * by;
        const int x = bid & 7;           // XCD id
        const int j = bid >> 3;
        bx = j % gx;
        by = x + 8 * (j / gx);
    }
    const int row0 = by * 256;
    const int col0 = bx * 128;

    const int wr = (wave >> 1) * 64;     // 0,64,128,192
    const int wc = (wave & 1) * 64;      // 0,64
    const int quad = lane >> 4;
    const int l16  = lane & 15;

    f32x4 acc[4][4] = {};

    // staging: A has 16 chunks (16 rows x 64B), wave w fills w and w+8;
    // B has 8 chunks, wave w fills w. global_load_lds dest = base + lane*16.
    const int srow  = lane >> 2;
    const int skoff = (lane & 3) * 8;
    const size_t A128 = (size_t)128 * lda;

    const int z = blockIdx.z;
    const _Float16* pa = A + (size_t)row0 * lda + (size_t)z * Ks
                           + (size_t)(wave * 16 + srow) * lda + skoff;
    const _Float16* pb = B + (size_t)col0 * ldb + (size_t)z * Ks
                           + (size_t)(wave * 16 + srow) * ldb + skoff;

    async_ld16(At[0] + wave * 512,       pa);
    async_ld16(At[0] + (wave + 8) * 512, pa + A128);
    async_ld16(Bt[0] + wave * 512,       pb);
    __syncthreads();

    int cur = 0;
    for (int k0 = 0; k0 < Ks; k0 += 32) {
        const int nxt = cur ^ 1;
        if (k0 + 32 < Ks) {
            async_ld16(At[nxt] + wave * 512,       pa + k0 + 32);
            async_ld16(At[nxt] + (wave + 8) * 512, pa + k0 + 32 + A128);
            async_ld16(Bt[nxt] + wave * 512,       pb + k0 + 32);
        }

        f16x8 af[4], bf[4];
        #pragma unroll
        for (int r = 0; r < 4; ++r)
            af[r] = *(const f16x8*)&At[cur][(wr + r * 16 + l16) * 32 + quad * 8];
        #pragma unroll
        for (int c = 0; c < 4; ++c)
            bf[c] = *(const f16x8*)&Bt[cur][(wc + c * 16 + l16) * 32 + quad * 8];

        #pragma unroll
        for (int r = 0; r < 4; ++r)
            #pragma unroll
            for (int c = 0; c < 4; ++c)
                acc[r][c] = __builtin_amdgcn_mfma_f32_16x16x32_f16(af[r], bf[c], acc[r][c], 0, 0, 0);

        __syncthreads();
        cur = nxt;
    }

    float* Cb; int ldc;
    if      (z == 0) { Cb = cd.p0; ldc = cd.l0; }
    else if (z == 1) { Cb = cd.p1; ldc = cd.l1; }
    else if (z == 2) { Cb = cd.p2; ldc = cd.l2; }
    else             { Cb = cd.p3; ldc = cd.l3; }

    // C/D layout: col = lane&15, row = quad*4 + reg   [verified m89/m91]
    #pragma unroll
    for (int r = 0; r < 4; ++r) {
        const int growb = row0 + wr + r * 16 + quad * 4;
        #pragma unroll
        for (int c = 0; c < 4; ++c) {
            const int gcol = col0 + wc + c * 16 + l16;
            #pragma unroll
            for (int i = 0; i < 4; ++i)
                __builtin_nontemporal_store(
                    acc[r][c][i], &Cb[(size_t)(growb + i) * ldc + gcol]);
        }
    }
}

// one block per row; reads S f32 row [4096], writes P fp16 IN PLACE over the
// first half of the row (all reads complete before first barrier -> safe).
__global__ __launch_bounds__(256) void softmax_rows(
    float* __restrict__ S, float scale)
{
    __shared__ float red[4];
    const int row = blockIdx.x;
    const int tid = threadIdx.x;
    const int wave = tid >> 6;
    const float4* Sr = (const float4*)(S + (size_t)row * 4096);

    float4 x[4];
    #pragma unroll
    for (int i = 0; i < 4; ++i) x[i] = Sr[tid + i * 256];

    float mx = -3.402823466e+38f;
    #pragma unroll
    for (int i = 0; i < 4; ++i)
        mx = fmaxf(mx, fmaxf(fmaxf(x[i].x, x[i].y), fmaxf(x[i].z, x[i].w)));
    #pragma unroll
    for (int off = 32; off > 0; off >>= 1) mx = fmaxf(mx, __shfl_down(mx, off));
    if ((tid & 63) == 0) red[wave] = mx;
    __syncthreads();
    mx = fmaxf(fmaxf(red[0], red[1]), fmaxf(red[2], red[3]));
    __syncthreads();

    float sum = 0.0f;
    #pragma unroll
    for (int i = 0; i < 4; ++i) {
        x[i].x = __expf(x[i].x - mx);
        x[i].y = __expf(x[i].y - mx);
        x[i].z = __expf(x[i].z - mx);
        x[i].w = __expf(x[i].w - mx);
        sum += x[i].x + x[i].y + x[i].z + x[i].w;
    }
    #pragma unroll
    for (int off = 32; off > 0; off >>= 1) sum += __shfl_down(sum, off);
    if ((tid & 63) == 0) red[wave] = sum;
    __syncthreads();
    sum = red[0] + red[1] + red[2] + red[3];

    const float inv = scale / sum;
    f16x4* Pr = (f16x4*)((_Float16*)S + (size_t)row * 8192);
    #pragma unroll
    for (int i = 0; i < 4; ++i) {
        f16x4 h;
        h.x = (_Float16)(x[i].x * inv);
        h.y = (_Float16)(x[i].y * inv);
        h.z = (_Float16)(x[i].z * inv);
        h.w = (_Float16)(x[i].w * inv);
        Pr[tid + i * 256] = h;
    }
}

// fused prep: [0,4096) transpose-cvt V tiles; [4096,6144) cvt Q,K to fp16.
__global__ __launch_bounds__(256) void prep(
    const float* __restrict__ Q, _Float16* __restrict__ Qh, int nQ4,
    const float* __restrict__ Kf, _Float16* __restrict__ Kh, int nK4,
    const float* __restrict__ V, _Float16* __restrict__ Vt, int rows, int cols)
{
    const int bid = blockIdx.x;
    if (bid < 4096) {
        __shared__ float tile[32][33];
        const int c0 = (bid & 31) * 32;
        const int r0 = (bid >> 5) * 32;
        const int tx = threadIdx.x & 31;
        const int ty = threadIdx.x >> 5;
        #pragma unroll
        for (int i = 0; i < 4; ++i)
            tile[ty * 4 + i][tx] = V[(size_t)(r0 + ty * 4 + i) * cols + c0 + tx];
        __syncthreads();
        #pragma unroll
        for (int i = 0; i < 4; ++i)
            Vt[(size_t)(c0 + ty * 4 + i) * rows + r0 + tx] = (_Float16)tile[tx][ty * 4 + i];
    } else {
        int i = (bid - 4096) * 256 + threadIdx.x;
        const int stride = 2048 * 256;
        const int tot = nQ4 + nK4;
        const float4* a = (const float4*)Q;
        const float4* b = (const float4*)Kf;
        for (; i < tot; i += stride) {
            const float4* s = (i < nQ4) ? (a + i) : (b + (i - nQ4));
            f16x4* dd = (i < nQ4) ? ((f16x4*)Qh + i) : ((f16x4*)Kh + (i - nQ4));
            float4 v = *s;
            f16x4 h;
            h.x = (_Float16)v.x; h.y = (_Float16)v.y;
            h.z = (_Float16)v.z; h.w = (_Float16)v.w;
            *dd = h;
        }
    }
}

// out[r][0:1024] += sum of nparts partials (each ptr + row stride in f32)
__global__ __launch_bounds__(256) void reduce_add(
    float4* __restrict__ out,
    const float* __restrict__ p1, int ld1,
    const float* __restrict__ p2, int ld2,
    const float* __restrict__ p3, int ld3,
    int nparts, int rows)
{
    int i = blockIdx.x * 256 + threadIdx.x;
    const int stride = gridDim.x * 256;
    const int tot = rows * 256;
    for (; i < tot; i += stride) {
        const int r = i >> 8, c = i & 255;
        float4 v = out[i];
        float4 a = ((const float4*)(p1 + (size_t)r * ld1))[c];
        v.x += a.x; v.y += a.y; v.z += a.z; v.w += a.w;
        if (nparts > 1) {
            float4 b = ((const float4*)(p2 + (size_t)r * ld2))[c];
            v.x += b.x; v.y += b.y; v.z += b.z; v.w += b.w;
        }
        if (nparts > 2) {
            float4 d = ((const float4*)(p3 + (size_t)r * ld3))[c];
            v.x += d.x; v.y += d.y; v.z += d.z; v.w += d.w;
        }
        out[i] = v;
    }
}

extern "C" void kernel_launch(void* const* d_in, const int* in_sizes, int n_in,
                              void* d_out, int out_size, void* d_ws, size_t ws_size,
                              hipStream_t stream) {
    const float* Q = (const float*)d_in[0];
    const float* K = (const float*)d_in[1];
    const float* V = (const float*)d_in[2];
    float* out = (float*)d_out;

    const int n = 4096, m = 4096, d = 1024, vdim = 1024;
    const float scale = 0.03125f;  // 1024^-0.5

    char* w = (char*)d_ws;
    _Float16* Qh = (_Float16*)w;                        // 8 MB
    _Float16* Kh = (_Float16*)(w + (8u << 20));         // 8 MB
    _Float16* Vt = (_Float16*)(w + (16u << 20));        // 8 MB
    char* rest = w + (24u << 20);
    size_t avail = ws_size > (24u << 20) ? ws_size - (24u << 20) : 0;

    // main path: nc=4096 single chunk (R4/R5 proved avail >= 64 MB).
    int nc;
    if      (avail >= (size_t)4096 * 16384)                       nc = 4096;
    else if (avail >= (size_t)2048 * 16384 + (size_t)2048 * 4096) nc = 2048;
    else if (avail >= (size_t)1024 * 16384 + (size_t)1024 * 4096) nc = 1024;
    else                                                          nc = 512;

    float* S = (float*)rest;                      // nc x 4096 f32
    float* pd1 = S + 2048;                        // dead-space partial, ld 4096
    float* pd2 = S + 3072;                        // dead-space partial, ld 4096
    // 3rd partial: nc==4096 -> Qh/Kh region (dead after QK, single chunk);
    // else dense region after S (allocation guaranteed by branch above).
    float* pde = (nc == 4096) ? (float*)w : (S + (size_t)nc * 4096);

    prep<<<dim3(6144), dim3(256), 0, stream>>>(
        Q, Qh, n * d / 4, K, Kh, m * d / 4, V, Vt, m, vdim);

    for (int r0 = 0; r0 < n; r0 += nc) {
        // S = Qc * Kh^T   [nc x m]; 256x128 tiles -> grid (m/128, nc/256)
        CDesc cs; cs.p0 = cs.p1 = cs.p2 = cs.p3 = S;
        cs.l0 = cs.l1 = cs.l2 = cs.l3 = m;
        gemm256<<<dim3(m / 128, nc / 256, 1), dim3(512), 0, stream>>>(
            Qh + (size_t)r0 * d, Kh, d, d, d, cs);

        softmax_rows<<<dim3(nc), dim3(256), 0, stream>>>(S, scale);

        // O = P * Vt^T, sk=4 over keys; z=0 -> out, z=1..3 -> partials
        float* o0 = out + (size_t)r0 * vdim;
        CDesc co;
        co.p0 = o0;  co.l0 = vdim;
        co.p1 = pd1; co.l1 = 4096;
        co.p2 = pd2; co.l2 = 4096;
        co.p3 = pde; co.l3 = vdim;
        gemm256<<<dim3(vdim / 128, nc / 256, 4), dim3(512), 0, stream>>>(
            (const _Float16*)S, Vt, m / 4, 2 * m, m, co);

        reduce_add<<<dim3(1024), dim3(256), 0, stream>>>(
            (float4*)o0, pd1, 4096, pd2, 4096, pde, vdim, 3, nc);
    }
}

// Round 8
// 223.541 us; speedup vs baseline: 1.0321x; 1.0052x over previous
//
#include <hip/hip_runtime.h>
#include <hip/hip_bf16.h>

typedef _Float16 f16x8 __attribute__((ext_vector_type(8)));
typedef _Float16 f16x4 __attribute__((ext_vector_type(4)));
typedef float f32x4 __attribute__((ext_vector_type(4)));

__device__ __forceinline__ void async_ld16(_Float16* lds, const _Float16* g) {
    __builtin_amdgcn_global_load_lds(
        (const __attribute__((address_space(1))) void*)g,
        (__attribute__((address_space(3))) void*)lds, 16, 0, 0);
}

// per-z C destinations (pointer + row stride in f32 elements)
struct CDesc {
    float *p0, *p1, *p2, *p3;
    int l0, l1, l2, l3;
};

// C = A[rows,K] * B[cols,K]^T, 256x128 tile, 8 waves (512 thr) as 4x2,
// each wave 64x64 via 4x4 of 16x16x32 MFMA. Double-buffered LDS.
// XCD swizzle (bid&7=XCD; verified FETCH 154->49MB).
// LDS XOR swizzle: row stride is 64B=16 banks, so straight slot mapping gives
// an 8-way bank conflict on fragment ds_read_b128 (measured 4.19M conflict
// cycles, ~3x LDS-port slowdown = the 57us plateau). LDS(row r, slot s)
// holds global k-chunk s^((r>>1)&3): staging permutes each lane's GLOBAL
// k-offset (DMA lane->LDS map must stay contiguous, m104/m108), readers
// fetch slot q^((l16>>1)&3). Each 8-lane phase then hits all 32 banks once.
__global__ __launch_bounds__(512) void gemm256(
    const _Float16* __restrict__ A,
    const _Float16* __restrict__ B,
    int Ks, int lda, int ldb, CDesc cd)
{
    __shared__ _Float16 At[2][256 * 32];
    __shared__ _Float16 Bt[2][128 * 32];

    const int tid  = threadIdx.x;
    const int wave = tid >> 6;           // 0..7
    const int lane = tid & 63;

    const int gx = gridDim.x;
    int bx = blockIdx.x, by = blockIdx.y;
    if ((gridDim.y & 7) == 0) {
        const int bid = bx + gx * by;
        const int x = bid & 7;           // XCD id
        const int j = bid >> 3;
        bx = j % gx;
        by = x + 8 * (j / gx);
    }
    const int row0 = by * 256;
    const int col0 = bx * 128;

    const int wr = (wave >> 1) * 64;     // 0,64,128,192
    const int wc = (wave & 1) * 64;      // 0,64
    const int quad = lane >> 4;
    const int l16  = lane & 15;

    f32x4 acc[4][4] = {};

    // staging: A has 16 chunks (16 rows x 64B), wave w fills w and w+8;
    // B has 8 chunks, wave w fills w. DMA dest = base + lane*16.
    // lane l -> LDS (row l>>2, slot l&3); global k-chunk = (l&3)^((l>>3)&3).
    const int srow  = lane >> 2;
    const int skoff = ((lane & 3) ^ ((lane >> 3) & 3)) * 8;
    const size_t A128 = (size_t)128 * lda;

    const int z = blockIdx.z;
    const _Float16* pa = A + (size_t)row0 * lda + (size_t)z * Ks
                           + (size_t)(wave * 16 + srow) * lda + skoff;
    const _Float16* pb = B + (size_t)col0 * ldb + (size_t)z * Ks
                           + (size_t)(wave * 16 + srow) * ldb + skoff;

    async_ld16(At[0] + wave * 512,       pa);
    async_ld16(At[0] + (wave + 8) * 512, pa + A128);
    async_ld16(Bt[0] + wave * 512,       pb);
    __syncthreads();

    // fragment read slot: global k-chunk quad lives at slot quad^((r>>1)&3);
    // for r = wr + rr*16 + l16 this reduces to quad^((l16>>1)&3).
    const int slot = (quad ^ ((l16 >> 1) & 3)) * 8;

    int cur = 0;
    for (int k0 = 0; k0 < Ks; k0 += 32) {
        const int nxt = cur ^ 1;
        if (k0 + 32 < Ks) {
            async_ld16(At[nxt] + wave * 512,       pa + k0 + 32);
            async_ld16(At[nxt] + (wave + 8) * 512, pa + k0 + 32 + A128);
            async_ld16(Bt[nxt] + wave * 512,       pb + k0 + 32);
        }

        f16x8 af[4], bf[4];
        #pragma unroll
        for (int r = 0; r < 4; ++r)
            af[r] = *(const f16x8*)&At[cur][(wr + r * 16 + l16) * 32 + slot];
        #pragma unroll
        for (int c = 0; c < 4; ++c)
            bf[c] = *(const f16x8*)&Bt[cur][(wc + c * 16 + l16) * 32 + slot];

        #pragma unroll
        for (int r = 0; r < 4; ++r)
            #pragma unroll
            for (int c = 0; c < 4; ++c)
                acc[r][c] = __builtin_amdgcn_mfma_f32_16x16x32_f16(af[r], bf[c], acc[r][c], 0, 0, 0);

        __syncthreads();
        cur = nxt;
    }

    float* Cb; int ldc;
    if      (z == 0) { Cb = cd.p0; ldc = cd.l0; }
    else if (z == 1) { Cb = cd.p1; ldc = cd.l1; }
    else if (z == 2) { Cb = cd.p2; ldc = cd.l2; }
    else             { Cb = cd.p3; ldc = cd.l3; }

    // C/D layout: col = lane&15, row = quad*4 + reg   [verified m89/m91]
    #pragma unroll
    for (int r = 0; r < 4; ++r) {
        const int growb = row0 + wr + r * 16 + quad * 4;
        #pragma unroll
        for (int c = 0; c < 4; ++c) {
            const int gcol = col0 + wc + c * 16 + l16;
            #pragma unroll
            for (int i = 0; i < 4; ++i)
                __builtin_nontemporal_store(
                    acc[r][c][i], &Cb[(size_t)(growb + i) * ldc + gcol]);
        }
    }
}

// one block per row; reads S f32 row [4096], writes P fp16 IN PLACE over the
// first half of the row (all reads complete before first barrier -> safe).
__global__ __launch_bounds__(256) void softmax_rows(
    float* __restrict__ S, float scale)
{
    __shared__ float red[4];
    const int row = blockIdx.x;
    const int tid = threadIdx.x;
    const int wave = tid >> 6;
    const float4* Sr = (const float4*)(S + (size_t)row * 4096);

    float4 x[4];
    #pragma unroll
    for (int i = 0; i < 4; ++i) x[i] = Sr[tid + i * 256];

    float mx = -3.402823466e+38f;
    #pragma unroll
    for (int i = 0; i < 4; ++i)
        mx = fmaxf(mx, fmaxf(fmaxf(x[i].x, x[i].y), fmaxf(x[i].z, x[i].w)));
    #pragma unroll
    for (int off = 32; off > 0; off >>= 1) mx = fmaxf(mx, __shfl_down(mx, off));
    if ((tid & 63) == 0) red[wave] = mx;
    __syncthreads();
    mx = fmaxf(fmaxf(red[0], red[1]), fmaxf(red[2], red[3]));
    __syncthreads();

    float sum = 0.0f;
    #pragma unroll
    for (int i = 0; i < 4; ++i) {
        x[i].x = __expf(x[i].x - mx);
        x[i].y = __expf(x[i].y - mx);
        x[i].z = __expf(x[i].z - mx);
        x[i].w = __expf(x[i].w - mx);
        sum += x[i].x + x[i].y + x[i].z + x[i].w;
    }
    #pragma unroll
    for (int off = 32; off > 0; off >>= 1) sum += __shfl_down(sum, off);
    if ((tid & 63) == 0) red[wave] = sum;
    __syncthreads();
    sum = red[0] + red[1] + red[2] + red[3];

    const float inv = scale / sum;
    f16x4* Pr = (f16x4*)((_Float16*)S + (size_t)row * 8192);
    #pragma unroll
    for (int i = 0; i < 4; ++i) {
        f16x4 h;
        h.x = (_Float16)(x[i].x * inv);
        h.y = (_Float16)(x[i].y * inv);
        h.z = (_Float16)(x[i].z * inv);
        h.w = (_Float16)(x[i].w * inv);
        Pr[tid + i * 256] = h;
    }
}

// fused prep: [0,4096) transpose-cvt V tiles; [4096,6144) cvt Q,K to fp16.
__global__ __launch_bounds__(256) void prep(
    const float* __restrict__ Q, _Float16* __restrict__ Qh, int nQ4,
    const float* __restrict__ Kf, _Float16* __restrict__ Kh, int nK4,
    const float* __restrict__ V, _Float16* __restrict__ Vt, int rows, int cols)
{
    const int bid = blockIdx.x;
    if (bid < 4096) {
        __shared__ float tile[32][33];
        const int c0 = (bid & 31) * 32;
        const int r0 = (bid >> 5) * 32;
        const int tx = threadIdx.x & 31;
        const int ty = threadIdx.x >> 5;
        #pragma unroll
        for (int i = 0; i < 4; ++i)
            tile[ty * 4 + i][tx] = V[(size_t)(r0 + ty * 4 + i) * cols + c0 + tx];
        __syncthreads();
        #pragma unroll
        for (int i = 0; i < 4; ++i)
            Vt[(size_t)(c0 + ty * 4 + i) * rows + r0 + tx] = (_Float16)tile[tx][ty * 4 + i];
    } else {
        int i = (bid - 4096) * 256 + threadIdx.x;
        const int stride = 2048 * 256;
        const int tot = nQ4 + nK4;
        const float4* a = (const float4*)Q;
        const float4* b = (const float4*)Kf;
        for (; i < tot; i += stride) {
            const float4* s = (i < nQ4) ? (a + i) : (b + (i - nQ4));
            f16x4* dd = (i < nQ4) ? ((f16x4*)Qh + i) : ((f16x4*)Kh + (i - nQ4));
            float4 v = *s;
            f16x4 h;
            h.x = (_Float16)v.x; h.y = (_Float16)v.y;
            h.z = (_Float16)v.z; h.w = (_Float16)v.w;
            *dd = h;
        }
    }
}

// out[r][0:1024] += sum of nparts partials (each ptr + row stride in f32)
__global__ __launch_bounds__(256) void reduce_add(
    float4* __restrict__ out,
    const float* __restrict__ p1, int ld1,
    const float* __restrict__ p2, int ld2,
    const float* __restrict__ p3, int ld3,
    int nparts, int rows)
{
    int i = blockIdx.x * 256 + threadIdx.x;
    const int stride = gridDim.x * 256;
    const int tot = rows * 256;
    for (; i < tot; i += stride) {
        const int r = i >> 8, c = i & 255;
        float4 v = out[i];
        float4 a = ((const float4*)(p1 + (size_t)r * ld1))[c];
        v.x += a.x; v.y += a.y; v.z += a.z; v.w += a.w;
        if (nparts > 1) {
            float4 b = ((const float4*)(p2 + (size_t)r * ld2))[c];
            v.x += b.x; v.y += b.y; v.z += b.z; v.w += b.w;
        }
        if (nparts > 2) {
            float4 d = ((const float4*)(p3 + (size_t)r * ld3))[c];
            v.x += d.x; v.y += d.y; v.z += d.z; v.w += d.w;
        }
        out[i] = v;
    }
}

extern "C" void kernel_launch(void* const* d_in, const int* in_sizes, int n_in,
                              void* d_out, int out_size, void* d_ws, size_t ws_size,
                              hipStream_t stream) {
    const float* Q = (const float*)d_in[0];
    const float* K = (const float*)d_in[1];
    const float* V = (const float*)d_in[2];
    float* out = (float*)d_out;

    const int n = 4096, m = 4096, d = 1024, vdim = 1024;
    const float scale = 0.03125f;  // 1024^-0.5

    char* w = (char*)d_ws;
    _Float16* Qh = (_Float16*)w;                        // 8 MB
    _Float16* Kh = (_Float16*)(w + (8u << 20));         // 8 MB
    _Float16* Vt = (_Float16*)(w + (16u << 20));        // 8 MB
    char* rest = w + (24u << 20);
    size_t avail = ws_size > (24u << 20) ? ws_size - (24u << 20) : 0;

    // main path: nc=4096 single chunk (R4-R7 confirm avail >= 64 MB).
    int nc;
    if      (avail >= (size_t)4096 * 16384)                       nc = 4096;
    else if (avail >= (size_t)2048 * 16384 + (size_t)2048 * 4096) nc = 2048;
    else if (avail >= (size_t)1024 * 16384 + (size_t)1024 * 4096) nc = 1024;
    else                                                          nc = 512;

    float* S = (float*)rest;                      // nc x 4096 f32
    float* pd1 = S + 2048;                        // dead-space partial, ld 4096
    float* pd2 = S + 3072;                        // dead-space partial, ld 4096
    // 3rd partial: nc==4096 -> Qh/Kh region (16 MB, dead after QK);
    // else dense region after S (allocation guaranteed by branch above).
    float* pde = (nc == 4096) ? (float*)w : (S + (size_t)nc * 4096);

    prep<<<dim3(6144), dim3(256), 0, stream>>>(
        Q, Qh, n * d / 4, K, Kh, m * d / 4, V, Vt, m, vdim);

    for (int r0 = 0; r0 < n; r0 += nc) {
        // S = Qc * Kh^T   [nc x m]; 256x128 tiles -> grid (m/128, nc/256)
        CDesc cs; cs.p0 = cs.p1 = cs.p2 = cs.p3 = S;
        cs.l0 = cs.l1 = cs.l2 = cs.l3 = m;
        gemm256<<<dim3(m / 128, nc / 256, 1), dim3(512), 0, stream>>>(
            Qh + (size_t)r0 * d, Kh, d, d, d, cs);

        softmax_rows<<<dim3(nc), dim3(256), 0, stream>>>(S, scale);

        // O = P * Vt^T, sk=4 over keys; z=0 -> out, z=1..3 -> partials
        float* o0 = out + (size_t)r0 * vdim;
        CDesc co;
        co.p0 = o0;  co.l0 = vdim;
        co.p1 = pd1; co.l1 = 4096;
        co.p2 = pd2; co.l2 = 4096;
        co.p3 = pde; co.l3 = vdim;
        gemm256<<<dim3(vdim / 128, nc / 256, 4), dim3(512), 0, stream>>>(
            (const _Float16*)S, Vt, m / 4, 2 * m, m, co);

        reduce_add<<<dim3(1024), dim3(256), 0, stream>>>(
            (float4*)o0, pd1, 4096, pd2, 4096, pde, vdim, 3, nc);
    }
}